// Round 2
// baseline (1009.330 us; speedup 1.0000x reference)
//
#include <hip/hip_runtime.h>

// LQR KKT solved via backward Riccati recursion + forward rollout.
// mu recovered via the STABLE costate identity mu_t = P_t x_t (mu_0 = -P_0 x0),
// not the raw adjoint recursion (which amplifies fp32 error by rho(A)~5.7/step).
//
// Dims: n_state=32, n_input=16, n_all=48, T=64.
//   backward: F = C_t + [A B]^T P_{t+1} [A B];  K_t = Fuu^{-1} Fux;
//             P_t = Fxx - Fxu K_t;  (P_T = 0)   [store K_t, P_t to d_ws]
//   forward:  u_t = -K_t x_t; x_{t+1} = A x_t + B u_t
//   mu:       mu_t = P_t x_t (t>=1);  mu_0 = -P_0 x_0   [parallel over all t]

namespace {

constexpr int NS  = 32;   // n_state
constexpr int NI  = 16;   // n_input
constexpr int NA  = 48;   // n_all
constexpr int TT  = 64;   // horizon
constexpr int NTH = 256;

__global__ __launch_bounds__(NTH, 1) void lqr_riccati(
    const float* __restrict__ A,
    const float* __restrict__ Bm,
    const float* __restrict__ C,     // [TT][NA][NA]
    const float* __restrict__ x0,
    float* __restrict__ out,         // [TT*NA] tau then [TT*NS] mu
    float* __restrict__ Kall,        // scratch: TT*NI*NS floats
    float* __restrict__ Pall)        // scratch: TT*NS*NS floats
{
  __shared__ float sAB[NS][NA];   // [A | B]
  __shared__ float sP [NS][NS];   // P_{t+1}
  __shared__ float sG [NS][NA];   // P @ [A B]
  __shared__ float sF [NA][NA];   // C_t + [A B]^T P [A B]; GJ on rows 32..47
  __shared__ float sPiv[NA];
  __shared__ float sMul[NI];
  __shared__ float sZ [TT][NA];   // trajectory z_t = (x_t, u_t)

  const int tid = threadIdx.x;

  // stage [A | B] and zero P
  for (int e = tid; e < NS * NA; e += NTH) {
    int i = e / NA, j = e - i * NA;
    sAB[i][j] = (j < NS) ? A[i * NS + j] : Bm[i * NI + (j - NS)];
  }
  for (int e = tid; e < NS * NS; e += NTH) sP[e >> 5][e & 31] = 0.0f;
  __syncthreads();

  // ---------------- backward Riccati ----------------
  for (int t = TT - 1; t >= 0; --t) {
    // G = P @ [A B]   (NS x NA)
    for (int e = tid; e < NS * NA; e += NTH) {
      int i = e / NA, k = e - i * NA;
      float acc = 0.0f;
      #pragma unroll
      for (int m = 0; m < NS; ++m) acc += sP[i][m] * sAB[m][k];
      sG[i][k] = acc;
    }
    __syncthreads();

    // F = C_t + [A B]^T G   (NA x NA)
    const float* Ct = C + (size_t)t * NA * NA;
    for (int e = tid; e < NA * NA; e += NTH) {
      int j = e / NA, k = e - j * NA;
      float acc = Ct[e];
      #pragma unroll
      for (int i = 0; i < NS; ++i) acc += sAB[i][j] * sG[i][k];
      sF[j][k] = acc;
    }
    __syncthreads();

    // Gauss-Jordan: reduce F_uu (rows/cols 32..47) to I; cols 0..31 become K.
    // F is SPD (C = WW^T/sqrt(48)+I, plus PSD term) -> no pivoting needed.
    for (int k = 0; k < NI; ++k) {
      if (tid < NA) sPiv[tid] = sF[NS + k][tid];
      else if (tid < NA + NI) sMul[tid - NA] = sF[NS + (tid - NA)][NS + k];
      __syncthreads();
      const float pr = 1.0f / sPiv[NS + k];
      for (int e = tid; e < NI * NA; e += NTH) {
        int i = e / NA, j = e - i * NA;
        if (i == k) sF[NS + i][j] = sPiv[j] * pr;
        else        sF[NS + i][j] -= sMul[i] * pr * sPiv[j];
      }
      __syncthreads();
    }

    // store K_t; then P <- Fxx - Fxu @ K, store P_t
    for (int e = tid; e < NI * NS; e += NTH) {
      int i = e >> 5, j = e & 31;
      Kall[(size_t)t * NI * NS + e] = sF[NS + i][j];
    }
    for (int e = tid; e < NS * NS; e += NTH) {
      int a = e >> 5, b = e & 31;
      float acc = sF[a][b];
      #pragma unroll
      for (int i = 0; i < NI; ++i) acc -= sF[a][NS + i] * sF[NS + i][b];
      sP[a][b] = acc;
      Pall[(size_t)t * NS * NS + e] = acc;
    }
    __syncthreads();
  }

  // ---------------- forward rollout ----------------
  if (tid < NS) sZ[0][tid] = x0[tid];
  __syncthreads();
  for (int t = 0; t < TT; ++t) {
    if (tid < NI) {
      float acc = 0.0f;
      #pragma unroll
      for (int j = 0; j < NS; ++j)
        acc += Kall[(size_t)t * NI * NS + tid * NS + j] * sZ[t][j];
      sZ[t][NS + tid] = -acc;   // u_t = -K_t x_t
    }
    __syncthreads();
    if (t < TT - 1 && tid < NS) {
      float acc = 0.0f;
      #pragma unroll
      for (int j = 0; j < NA; ++j) acc += sAB[tid][j] * sZ[t][j];
      sZ[t + 1][tid] = acc;     // x_{t+1}
    }
    __syncthreads();
  }

  // write tau
  for (int e = tid; e < TT * NA; e += NTH) {
    int t = e / NA;
    out[e] = sZ[t][e - t * NA];
  }

  // ---------------- mu_t = (t==0 ? -1 : +1) * P_t x_t  (parallel over t) ----
  for (int e = tid; e < TT * NS; e += NTH) {
    int t = e >> 5, i = e & 31;
    const float* Pt = Pall + (size_t)t * NS * NS + i * NS;
    float acc = 0.0f;
    #pragma unroll
    for (int j = 0; j < NS; ++j) acc += Pt[j] * sZ[t][j];
    out[NA * TT + e] = (t == 0) ? -acc : acc;
  }
}

} // namespace

extern "C" void kernel_launch(void* const* d_in, const int* in_sizes, int n_in,
                              void* d_out, int out_size, void* d_ws, size_t ws_size,
                              hipStream_t stream) {
  const float* A  = (const float*)d_in[0];
  const float* B  = (const float*)d_in[1];
  const float* C  = (const float*)d_in[2];
  // d_in[3] is T (==64, compile-time constant here)
  const float* x0 = (const float*)d_in[4];
  float* out  = (float*)d_out;
  float* Kall = (float*)d_ws;                       // TT*NI*NS floats = 128 KB
  float* Pall = (float*)d_ws + (size_t)TT * NI * NS; // TT*NS*NS floats = 256 KB

  hipLaunchKernelGGL(lqr_riccati, dim3(1), dim3(NTH), 0, stream,
                     A, B, C, x0, out, Kall, Pall);
}

// Round 3
// 389.606 us; speedup vs baseline: 2.5906x; 2.5906x over previous
//
#include <hip/hip_runtime.h>

// LQR KKT via backward Riccati + forward rollout; mu_t = P_t x_t (stable).
// Round-3 structure: wave-register Gauss-Jordan (no barriers), float4
// register-blocked LDS GEMMs, C_t register prefetch.
//
// Dims: n_state=32, n_input=16, n_all=48, T=64.

namespace {

constexpr int NS  = 32;
constexpr int NI  = 16;
constexpr int NA  = 48;
constexpr int TT  = 64;
constexpr int NTH = 256;

__device__ __forceinline__ void fma4(float4& a, float s, const float4& b) {
  a.x += s * b.x; a.y += s * b.y; a.z += s * b.z; a.w += s * b.w;
}
__device__ __forceinline__ void fms4(float4& a, float s, const float4& b) {
  a.x -= s * b.x; a.y -= s * b.y; a.z -= s * b.z; a.w -= s * b.w;
}

__global__ __launch_bounds__(NTH, 1) void lqr_riccati(
    const float* __restrict__ A,
    const float* __restrict__ Bm,
    const float* __restrict__ C,     // [TT][NA][NA]
    const float* __restrict__ x0,
    float* __restrict__ out,         // [TT*NA] tau then [TT*NS] mu
    float* __restrict__ Kall,        // scratch: TT*NI*NS floats
    float* __restrict__ Pall)        // scratch: TT*NS*NS floats
{
  __shared__ float sAB[NS][NA];   // [A | B]
  __shared__ float sP [NS][NS];   // P_{t+1}
  __shared__ float sG [NS][NA];   // P @ [A B]
  __shared__ float sF [NA][NA];   // C_t + [A B]^T P [A B]
  __shared__ float sK [NI][NS];   // K_t
  __shared__ float sZ [TT][NA];   // trajectory z_t = (x_t, u_t)

  const int tid  = threadIdx.x;
  const int lane = tid & 63;
  const int wid  = tid >> 6;

  // stage [A | B], zero P
  for (int e = tid; e < NS * NA; e += NTH) {
    int i = e / NA, j = e - i * NA;
    sAB[i][j] = (j < NS) ? A[i * NS + j] : Bm[i * NI + (j - NS)];
  }
  for (int e = tid; e < NS * NS; e += NTH) sP[e >> 5][e & 31] = 0.0f;
  __syncthreads();

  // ---------------- backward Riccati ----------------
  for (int t = TT - 1; t >= 0; --t) {
    // prefetch C_t (576 float4 blocks; coalesced). Consumed by F below ->
    // latency hides under the G GEMM.
    const float4* Ct4 = (const float4*)(C + (size_t)t * NA * NA);
    float4 c0 = Ct4[tid];
    float4 c1 = Ct4[tid + 256];
    float4 c2 = (tid < 64) ? Ct4[tid + 512] : make_float4(0.f, 0.f, 0.f, 0.f);

    // G = P @ [A B]  (32x48 = 384 float4-blocks)
    {
      int i = tid / 12, kq = tid % 12;
      float4 acc = make_float4(0.f, 0.f, 0.f, 0.f);
      #pragma unroll
      for (int m = 0; m < NS; ++m)
        fma4(acc, sP[i][m], *(const float4*)&sAB[m][4 * kq]);
      *(float4*)&sG[i][4 * kq] = acc;
      if (tid < 128) {
        int blk = tid + 256, i2 = blk / 12, k2 = blk % 12;
        float4 a2 = make_float4(0.f, 0.f, 0.f, 0.f);
        #pragma unroll
        for (int m = 0; m < NS; ++m)
          fma4(a2, sP[i2][m], *(const float4*)&sAB[m][4 * k2]);
        *(float4*)&sG[i2][4 * k2] = a2;
      }
    }
    __syncthreads();

    // F = C_t + [A B]^T G  (48x48 = 576 float4-blocks)
    {
      int j = tid / 12, kq = tid % 12;
      float4 acc = c0;
      #pragma unroll
      for (int i = 0; i < NS; ++i)
        fma4(acc, sAB[i][j], *(const float4*)&sG[i][4 * kq]);
      *(float4*)&sF[j][4 * kq] = acc;

      int b1 = tid + 256, j1 = b1 / 12, k1 = b1 % 12;
      float4 a1 = c1;
      #pragma unroll
      for (int i = 0; i < NS; ++i)
        fma4(a1, sAB[i][j1], *(const float4*)&sG[i][4 * k1]);
      *(float4*)&sF[j1][4 * k1] = a1;

      if (tid < 64) {
        int b2 = tid + 512, j2 = b2 / 12, k2 = b2 % 12;
        float4 a2 = c2;
        #pragma unroll
        for (int i = 0; i < NS; ++i)
          fma4(a2, sAB[i][j2], *(const float4*)&sG[i][4 * k2]);
        *(float4*)&sF[j2][4 * k2] = a2;
      }
    }
    __syncthreads();

    // Gauss-Jordan on M = [Fuu | Fux] (16x48), entirely in wave 0 registers.
    // lane c holds column c of M: c<16 -> Fuu[:,c], c>=16 -> Fux[:,c-16].
    // SPD (C = WW^T/sqrt(48)+I plus PSD) -> no pivoting.
    if (wid == 0) {
      const int col = (lane < 16) ? (NS + lane) : (lane - 16);
      float f[NI];
      #pragma unroll
      for (int i = 0; i < NI; ++i) f[i] = sF[NS + i][col];
      #pragma unroll
      for (int k = 0; k < NI; ++k) {
        float m[NI];
        #pragma unroll
        for (int i = 0; i < NI; ++i) m[i] = __shfl(f[i], k);
        const float inv = 1.0f / m[k];
        f[k] *= inv;
        #pragma unroll
        for (int i = 0; i < NI; ++i)
          if (i != k) f[i] -= m[i] * f[k];
      }
      // cols 16..47 now hold K (16x32)
      if (lane >= 16 && lane < 48) {
        const int b = lane - 16;
        #pragma unroll
        for (int i = 0; i < NI; ++i) {
          sK[i][b] = f[i];
          Kall[(size_t)t * NI * NS + i * NS + b] = f[i];
        }
      }
    }
    __syncthreads();

    // P = Fxx - Fxu @ K  (32x32 = 256 float4-blocks, one per thread)
    {
      int a = tid >> 3, bq = tid & 7;
      float4 acc = *(const float4*)&sF[a][4 * bq];
      #pragma unroll
      for (int i = 0; i < NI; ++i)
        fms4(acc, sF[a][NS + i], *(const float4*)&sK[i][4 * bq]);
      *(float4*)&sP[a][4 * bq] = acc;
      *((float4*)Pall + (size_t)t * 256 + tid) = acc;
    }
    __syncthreads();
  }

  // ---------------- forward rollout ----------------
  if (tid < NS) sZ[0][tid] = x0[tid];
  __syncthreads();
  for (int t = 0; t < TT; ++t) {
    if (tid < NI) {
      const float4* Kr = (const float4*)(Kall + (size_t)t * NI * NS + tid * NS);
      float acc = 0.0f;
      #pragma unroll
      for (int q = 0; q < 8; ++q) {
        float4 k4 = Kr[q];
        acc += k4.x * sZ[t][4 * q]     + k4.y * sZ[t][4 * q + 1]
             + k4.z * sZ[t][4 * q + 2] + k4.w * sZ[t][4 * q + 3];
      }
      sZ[t][NS + tid] = -acc;        // u_t = -K_t x_t
    }
    __syncthreads();
    if (t < TT - 1 && tid < NS) {
      float acc = 0.0f;
      #pragma unroll
      for (int q = 0; q < 12; ++q) {
        float4 a4 = *(const float4*)&sAB[tid][4 * q];
        acc += a4.x * sZ[t][4 * q]     + a4.y * sZ[t][4 * q + 1]
             + a4.z * sZ[t][4 * q + 2] + a4.w * sZ[t][4 * q + 3];
      }
      sZ[t + 1][tid] = acc;          // x_{t+1}
    }
    __syncthreads();
  }

  // write tau
  for (int e = tid; e < TT * NA; e += NTH) {
    int t = e / NA;
    out[e] = sZ[t][e - t * NA];
  }

  // mu_t = (t==0 ? -1 : +1) * P_t x_t  (parallel over all t)
  for (int e = tid; e < TT * NS; e += NTH) {
    int t = e >> 5, i = e & 31;
    const float4* Pr = (const float4*)(Pall + (size_t)t * NS * NS + i * NS);
    float acc = 0.0f;
    #pragma unroll
    for (int q = 0; q < 8; ++q) {
      float4 p4 = Pr[q];
      acc += p4.x * sZ[t][4 * q]     + p4.y * sZ[t][4 * q + 1]
           + p4.z * sZ[t][4 * q + 2] + p4.w * sZ[t][4 * q + 3];
    }
    out[NA * TT + e] = (t == 0) ? -acc : acc;
  }
}

} // namespace

extern "C" void kernel_launch(void* const* d_in, const int* in_sizes, int n_in,
                              void* d_out, int out_size, void* d_ws, size_t ws_size,
                              hipStream_t stream) {
  const float* A  = (const float*)d_in[0];
  const float* B  = (const float*)d_in[1];
  const float* C  = (const float*)d_in[2];
  // d_in[3] is T (==64, compile-time constant here)
  const float* x0 = (const float*)d_in[4];
  float* out  = (float*)d_out;
  float* Kall = (float*)d_ws;                        // 128 KB
  float* Pall = (float*)d_ws + (size_t)TT * NI * NS; // 256 KB

  hipLaunchKernelGGL(lqr_riccati, dim3(1), dim3(NTH), 0, stream,
                     A, B, C, x0, out, Kall, Pall);
}